// Round 5
// baseline (983.946 us; speedup 1.0000x reference)
//
#include <hip/hip_runtime.h>

#define N_NODES 100000
#define N_EDGES 1250000
#define D 64
#define BUCKET_BITS 7                 // 128 nodes per bucket
#define BUCKET_SZ (1 << BUCKET_BITS)
#define NBUCK 782                     // ceil(100000 / 128)
#define TILE_PAD 68                   // 128-node tile row stride (floats): 272B, 16B-aligned
#define HIST_BLOCKS 128

// ---------------------------------------------------------------------------
// Workspace layout (bytes):
//   packed  @ 0          : E int2  = 10,000,000   (src | dst_local<<20, e) binned by bucket
//   bcounts @ 10,000,000 : NBUCK i32
//   bstarts @ 10,004,096 : (NBUCK+1) i32
//   bcursor @ 10,008,192 : NBUCK i32
// ---------------------------------------------------------------------------

// K1: bucket histogram, LDS-aggregated.
__global__ __launch_bounds__(256) void bucket_hist_kernel(const int* __restrict__ dst,
                                                          int* __restrict__ bcounts) {
    __shared__ int lhist[NBUCK];
    int t = threadIdx.x;
    for (int j = t; j < NBUCK; j += 256) lhist[j] = 0;
    __syncthreads();
    int gid = blockIdx.x * 256 + t;
    int gsz = HIST_BLOCKS * 256;
    for (int i = gid; i < N_EDGES; i += gsz)
        atomicAdd(&lhist[dst[i] >> BUCKET_BITS], 1);
    __syncthreads();
    for (int j = t; j < NBUCK; j += 256)
        if (lhist[j]) atomicAdd(&bcounts[j], lhist[j]);
}

// K2: exclusive scan of NBUCK bucket counts (single block).
__global__ __launch_bounds__(1024) void bucket_scan_kernel(const int* __restrict__ bcounts,
                                                           int* __restrict__ bstarts,
                                                           int* __restrict__ bcursor) {
    __shared__ int tmp[1024];
    int t = threadIdx.x;
    int v = (t < NBUCK) ? bcounts[t] : 0;
    tmp[t] = v;
    __syncthreads();
#pragma unroll
    for (int off = 1; off < 1024; off <<= 1) {
        int x = (t >= off) ? tmp[t - off] : 0;
        __syncthreads();
        tmp[t] += x;
        __syncthreads();
    }
    if (t < NBUCK) {
        int s = tmp[t] - v;   // exclusive
        bstarts[t] = s;
        bcursor[t] = s;
    }
    if (t == 0) bstarts[NBUCK] = N_EDGES;
}

// K3: bin edges into bucket-contiguous regions. Pack src (17b) + dst_local (7b) + e.
__global__ __launch_bounds__(256) void bin_edges_kernel(const int* __restrict__ src,
                                                        const int* __restrict__ dst,
                                                        const float* __restrict__ e,
                                                        int* __restrict__ bcursor,
                                                        int2* __restrict__ packed) {
    int i = blockIdx.x * 256 + threadIdx.x;
    if (i >= N_EDGES) return;
    int d = dst[i];
    int bucket = d >> BUCKET_BITS;
    int dlocal = d & (BUCKET_SZ - 1);
    int pos = atomicAdd(&bcursor[bucket], 1);
    packed[pos] = make_int2(src[i] | (dlocal << 20), __float_as_int(e[i]));
}

// K4: per-bucket fused gather + linear.
//  phase A: accumulate ft tile (128 x 64 fp32) in LDS via ds_add_f32;
//           lane d handles feature d, 2-edge ILP per wave.
//  phase B: tile GEMM with W (wave-uniform reads) + bias, store out.
__global__ __launch_bounds__(256) void gather_tile_kernel(const float* __restrict__ h,
                                                          const int2* __restrict__ packed,
                                                          const int* __restrict__ bstarts,
                                                          const float* __restrict__ W,
                                                          const float* __restrict__ bias,
                                                          float* __restrict__ out) {
    __shared__ __align__(16) float tile[BUCKET_SZ * TILE_PAD];
    int t = threadIdx.x;
    int bucket = blockIdx.x;

    for (int i = t; i < BUCKET_SZ * TILE_PAD; i += 256) tile[i] = 0.f;
    __syncthreads();

    int start = bstarts[bucket];
    int end = bstarts[bucket + 1];
    int wid = t >> 6;
    int lane = t & 63;

    // phase A: 4 waves interleave over the bucket's edge list, 2 edges in flight
    int k = start + wid;
    for (; k + 4 < end; k += 8) {
        int2 p0 = packed[k];
        int2 p1 = packed[k + 4];
        int s0 = p0.x & 0xFFFFF, dl0 = p0.x >> 20;
        int s1 = p1.x & 0xFFFFF, dl1 = p1.x >> 20;
        float v0 = h[s0 * D + lane] * __int_as_float(p0.y);
        float v1 = h[s1 * D + lane] * __int_as_float(p1.y);
        atomicAdd(&tile[dl0 * TILE_PAD + lane], v0);
        atomicAdd(&tile[dl1 * TILE_PAD + lane], v1);
    }
    for (; k < end; k += 4) {
        int2 p = packed[k];
        int s = p.x & 0xFFFFF, dl = p.x >> 20;
        float v = h[s * D + lane] * __int_as_float(p.y);
        atomicAdd(&tile[dl * TILE_PAD + lane], v);
    }
    __syncthreads();

    // phase B: thread t -> node (t & 127), column half (t >> 7) * 32
    int node = t & 127;
    int half = t >> 7;
    int gnode = bucket * BUCKET_SZ + node;
    if (gnode >= N_NODES) return;

    float4 fr[16];
    const float4* frow = (const float4*)&tile[node * TILE_PAD];
#pragma unroll
    for (int i = 0; i < 16; ++i) fr[i] = frow[i];

    float4* orow = (float4*)(out + gnode * D + half * 32);
    const float4* W4 = (const float4*)W;

#pragma unroll
    for (int cc = 0; cc < 2; ++cc) {
        float acc[16];
        int c0 = half * 32 + cc * 16;
#pragma unroll
        for (int j = 0; j < 16; ++j) acc[j] = bias[c0 + j];
#pragma unroll
        for (int i = 0; i < 16; ++i) {
            float4 f = fr[i];
#pragma unroll
            for (int j = 0; j < 16; ++j) {
                float4 w = W4[(c0 + j) * 16 + i];
                acc[j] += f.x * w.x + f.y * w.y + f.z * w.z + f.w * w.w;
            }
        }
#pragma unroll
        for (int j4 = 0; j4 < 4; ++j4)
            orow[cc * 4 + j4] = make_float4(acc[j4 * 4], acc[j4 * 4 + 1],
                                            acc[j4 * 4 + 2], acc[j4 * 4 + 3]);
    }
}

// ---------------------------------------------------------------------------
extern "C" void kernel_launch(void* const* d_in, const int* in_sizes, int n_in,
                              void* d_out, int out_size, void* d_ws, size_t ws_size,
                              hipStream_t stream) {
    const float* h   = (const float*)d_in[0];
    const float* e   = (const float*)d_in[1];
    const int*   src = (const int*)d_in[2];
    const int*   dst = (const int*)d_in[3];
    const float* W   = (const float*)d_in[4];
    const float* b   = (const float*)d_in[5];
    float* out = (float*)d_out;

    char* ws = (char*)d_ws;
    int2* packed  = (int2*)(ws);
    int*  bcounts = (int*) (ws + 10000000);
    int*  bstarts = (int*) (ws + 10004096);
    int*  bcursor = (int*) (ws + 10008192);

    hipMemsetAsync(bcounts, 0, NBUCK * sizeof(int), stream);
    bucket_hist_kernel<<<HIST_BLOCKS, 256, 0, stream>>>(dst, bcounts);
    bucket_scan_kernel<<<1, 1024, 0, stream>>>(bcounts, bstarts, bcursor);
    bin_edges_kernel<<<(N_EDGES + 255) / 256, 256, 0, stream>>>(src, dst, e, bcursor, packed);
    gather_tile_kernel<<<NBUCK, 256, 0, stream>>>(h, packed, bstarts, W, b, out);
}

// Round 6
// 244.909 us; speedup vs baseline: 4.0176x; 4.0176x over previous
//
#include <hip/hip_runtime.h>

#define N_NODES 100000
#define N_EDGES 1250000
#define D 64
#define BUCKET_BITS 7                  // 128 nodes / bucket
#define BUCKET_SZ 128
#define NBUCK 782                      // ceil(100000/128)
#define EPT 16                         // edges per thread in bin_edges
#define EPB (EPT * 256)                // 4096 edges per block
#define BIN_BLOCKS ((N_EDGES + EPB - 1) / EPB)   // 306
#define CAP 2560                       // max edges per bucket (mean 1600, std 40)
#define HIST_BLOCKS 128

// ---------------------------------------------------------------------------
// Workspace layout (bytes):
//   packed  @ 0          : E int2      = 10,000,000  (src|dlocal<<20, e) bucket-binned
//   bcounts @ 10,000,000 : NBUCK i32
//   bstarts @ 10,004,096 : (NBUCK+1) i32
//   gcursor @ 10,008,192 : NBUCK i32
//   g       @ 10,012,288 : N*64 f32    = 25,600,000  (h @ W^T)
// total ~= 35.6 MB
// ---------------------------------------------------------------------------

// g = h @ W^T (fp32 vector GEMM, LDS-staged; unchanged from R4 — not the rock).
__global__ __launch_bounds__(256) void transform_kernel(const float* __restrict__ h,
                                                        const float* __restrict__ W,
                                                        float* __restrict__ g) {
    __shared__ float4 hs[64 * 17];
    __shared__ float4 ws4[64 * 17];
    int t = threadIdx.x;
    int n0 = blockIdx.x * 64;
#pragma unroll
    for (int k = 0; k < 4; ++k) {
        int f = t + k * 256;
        int r = f >> 4, c = f & 15;
        float4 hv = make_float4(0.f, 0.f, 0.f, 0.f);
        if (n0 + r < N_NODES) hv = ((const float4*)h)[(n0 + r) * 16 + c];
        hs[r * 17 + c] = hv;
        ws4[r * 17 + c] = ((const float4*)W)[f];
    }
    __syncthreads();

    int r = t >> 2;
    int oq = t & 3;
    float acc[16];
#pragma unroll
    for (int j = 0; j < 16; ++j) acc[j] = 0.f;

    for (int d4 = 0; d4 < 16; ++d4) {
        float4 hv = hs[r * 17 + d4];
#pragma unroll
        for (int j = 0; j < 16; ++j) {
            float4 wv = ws4[(oq * 16 + j) * 17 + d4];
            acc[j] += hv.x * wv.x + hv.y * wv.y + hv.z * wv.z + hv.w * wv.w;
        }
    }

    int n = n0 + r;
    if (n < N_NODES) {
        float4* gr = (float4*)(g + n * D + oq * 16);
        gr[0] = make_float4(acc[0], acc[1], acc[2], acc[3]);
        gr[1] = make_float4(acc[4], acc[5], acc[6], acc[7]);
        gr[2] = make_float4(acc[8], acc[9], acc[10], acc[11]);
        gr[3] = make_float4(acc[12], acc[13], acc[14], acc[15]);
    }
}

// K1: bucket histogram, LDS-aggregated (782 bins).
__global__ __launch_bounds__(256) void bucket_hist_kernel(const int* __restrict__ dst,
                                                          int* __restrict__ bcounts) {
    __shared__ int lhist[NBUCK];
    int t = threadIdx.x;
    for (int j = t; j < NBUCK; j += 256) lhist[j] = 0;
    __syncthreads();
    int gid = blockIdx.x * 256 + t;
    int gsz = HIST_BLOCKS * 256;
    for (int i = gid; i < N_EDGES; i += gsz)
        atomicAdd(&lhist[dst[i] >> BUCKET_BITS], 1);
    __syncthreads();
    for (int j = t; j < NBUCK; j += 256)
        if (lhist[j]) atomicAdd(&bcounts[j], lhist[j]);
}

// K2: exclusive scan of bucket counts (single block, 1024 >= NBUCK).
__global__ __launch_bounds__(1024) void bucket_scan_kernel(const int* __restrict__ bcounts,
                                                           int* __restrict__ bstarts,
                                                           int* __restrict__ gcursor) {
    __shared__ int tmp[1024];
    int t = threadIdx.x;
    int v = (t < NBUCK) ? bcounts[t] : 0;
    tmp[t] = v;
    __syncthreads();
#pragma unroll
    for (int off = 1; off < 1024; off <<= 1) {
        int x = (t >= off) ? tmp[t - off] : 0;
        __syncthreads();
        tmp[t] += x;
        __syncthreads();
    }
    if (t < NBUCK) {
        int s = tmp[t] - v;
        bstarts[t] = s;
        gcursor[t] = s;
    }
    if (t == 0) bstarts[NBUCK] = N_EDGES;
}

// K3: bin edges into bucket regions with block-level LDS ranking.
// One global slot-range reservation per (block,bucket) -> ~240k atomics,
// writes cluster into ~5-edge runs (L2-hot, low dirty-line amplification).
__global__ __launch_bounds__(256) void bin_edges_kernel(const int* __restrict__ src,
                                                        const int* __restrict__ dst,
                                                        const float* __restrict__ e,
                                                        int* __restrict__ gcursor,
                                                        int2* __restrict__ packed) {
    __shared__ int lhist[NBUCK];   // counts, then reused as per-block gbase
    int t = threadIdx.x;
    for (int j = t; j < NBUCK; j += 256) lhist[j] = 0;
    __syncthreads();

    int b[EPT], r[EPT], sv[EPT];
    float ev[EPT];
    int base = blockIdx.x * EPB;
#pragma unroll
    for (int j = 0; j < EPT; ++j) {
        int i = base + j * 256 + t;
        b[j] = -1;
        if (i < N_EDGES) {
            int d = dst[i];
            b[j] = d >> BUCKET_BITS;
            sv[j] = src[i] | ((d & (BUCKET_SZ - 1)) << 20);
            ev[j] = e[i];
            r[j] = atomicAdd(&lhist[b[j]], 1);
        }
    }
    __syncthreads();

    // reserve global ranges; lhist[x] becomes this block's base for bucket x
    for (int x = t; x < NBUCK; x += 256) {
        int c = lhist[x];
        lhist[x] = (c > 0) ? atomicAdd(&gcursor[x], c) : 0;
    }
    __syncthreads();

#pragma unroll
    for (int j = 0; j < EPT; ++j) {
        if (b[j] >= 0) {
            int pos = lhist[b[j]] + r[j];
            packed[pos] = make_int2(sv[j], __float_as_int(ev[j]));
        }
    }
}

// K4: per-bucket gather. Counting-sort the bucket's edges by node in LDS,
// then one wave per node-group: lane d accumulates feature d over the node's
// edge list ((src,e) broadcast from LDS, g-rows coalesced 256B, 4-deep ILP).
__global__ __launch_bounds__(256) void gather_bucket_kernel(const float* __restrict__ g,
                                                            const int2* __restrict__ packed,
                                                            const int* __restrict__ bstarts,
                                                            const float* __restrict__ bias,
                                                            float* __restrict__ out) {
    __shared__ int2 eds[CAP];
    __shared__ int nhist[BUCKET_SZ];
    __shared__ int nbase[BUCKET_SZ];
    __shared__ int ncur[BUCKET_SZ];
    __shared__ int tmp[BUCKET_SZ];

    int t = threadIdx.x;
    int bk = blockIdx.x;
    int start = bstarts[bk];
    int cnt = bstarts[bk + 1] - start;
    if (cnt > CAP) cnt = CAP;   // safety clamp (mean 1600, CAP=2560 ~ +24 sigma)

    if (t < BUCKET_SZ) nhist[t] = 0;
    __syncthreads();

    // pass 1: per-node histogram (coalesced global read, L2/L3-hot region)
    for (int i = t; i < cnt; i += 256) {
        int2 p = packed[start + i];
        atomicAdd(&nhist[(p.x >> 20) & (BUCKET_SZ - 1)], 1);
    }
    __syncthreads();

    // exclusive scan of 128 bins (Hillis-Steele, 7 steps)
    if (t < BUCKET_SZ) tmp[t] = nhist[t];
    __syncthreads();
#pragma unroll
    for (int off = 1; off < BUCKET_SZ; off <<= 1) {
        int x = 0;
        if (t < BUCKET_SZ && t >= off) x = tmp[t - off];
        __syncthreads();
        if (t < BUCKET_SZ) tmp[t] += x;
        __syncthreads();
    }
    if (t < BUCKET_SZ) {
        int s = tmp[t] - nhist[t];
        nbase[t] = s;
        ncur[t] = s;
    }
    __syncthreads();

    // pass 2: re-read edges (L2-hot), scatter into node-sorted LDS order
    for (int i = t; i < cnt; i += 256) {
        int2 p = packed[start + i];
        int dl = (p.x >> 20) & (BUCKET_SZ - 1);
        int pos = atomicAdd(&ncur[dl], 1);
        eds[pos] = p;
    }
    __syncthreads();

    // per-node gather: wave w handles nodes [w*32, w*32+32)
    int w = t >> 6;
    int lane = t & 63;
    float bv = bias[lane];
    for (int jj = 0; jj < 32; ++jj) {
        int n = w * 32 + jj;
        int gn = bk * BUCKET_SZ + n;
        int s = nbase[n];
        int c = nhist[n];
        float acc = bv;
        int k = 0;
        for (; k + 4 <= c; k += 4) {
            int2 p0 = eds[s + k];
            int2 p1 = eds[s + k + 1];
            int2 p2 = eds[s + k + 2];
            int2 p3 = eds[s + k + 3];
            float g0 = g[(p0.x & 0xFFFFF) * D + lane];
            float g1 = g[(p1.x & 0xFFFFF) * D + lane];
            float g2 = g[(p2.x & 0xFFFFF) * D + lane];
            float g3 = g[(p3.x & 0xFFFFF) * D + lane];
            acc += __int_as_float(p0.y) * g0;
            acc += __int_as_float(p1.y) * g1;
            acc += __int_as_float(p2.y) * g2;
            acc += __int_as_float(p3.y) * g3;
        }
        for (; k < c; ++k) {
            int2 p = eds[s + k];
            acc += __int_as_float(p.y) * g[(p.x & 0xFFFFF) * D + lane];
        }
        if (gn < N_NODES) out[gn * D + lane] = acc;
    }
}

// ---------------------------------------------------------------------------
extern "C" void kernel_launch(void* const* d_in, const int* in_sizes, int n_in,
                              void* d_out, int out_size, void* d_ws, size_t ws_size,
                              hipStream_t stream) {
    const float* h   = (const float*)d_in[0];
    const float* e   = (const float*)d_in[1];
    const int*   src = (const int*)d_in[2];
    const int*   dst = (const int*)d_in[3];
    const float* W   = (const float*)d_in[4];
    const float* b   = (const float*)d_in[5];
    float* out = (float*)d_out;

    char* ws = (char*)d_ws;
    int2*  packed  = (int2*) (ws);
    int*   bcounts = (int*)  (ws + 10000000);
    int*   bstarts = (int*)  (ws + 10004096);
    int*   gcursor = (int*)  (ws + 10008192);
    float* g       = (float*)(ws + 10012288);

    // 1) g = h @ W^T
    transform_kernel<<<(N_NODES + 63) / 64, 256, 0, stream>>>(h, W, g);

    // 2) bucket sort (coarse)
    hipMemsetAsync(bcounts, 0, NBUCK * sizeof(int), stream);
    bucket_hist_kernel<<<HIST_BLOCKS, 256, 0, stream>>>(dst, bcounts);
    bucket_scan_kernel<<<1, 1024, 0, stream>>>(bcounts, bstarts, gcursor);
    bin_edges_kernel<<<BIN_BLOCKS, 256, 0, stream>>>(src, dst, e, gcursor, packed);

    // 3) per-bucket LDS sub-sort + gather + bias
    gather_bucket_kernel<<<NBUCK, 256, 0, stream>>>(g, packed, bstarts, b, out);
}

// Round 7
// 224.782 us; speedup vs baseline: 4.3773x; 1.0895x over previous
//
#include <hip/hip_runtime.h>

#define N_NODES 100000
#define N_EDGES 1250000
#define D 64
#define BUCKET_BITS 7                  // 128 nodes / bucket
#define BUCKET_SZ 128
#define NBUCK 782                      // ceil(100000/128)
#define CAP 2560                       // fixed bucket capacity (mean 1600, sigma ~40)
#define EPT 16                         // edges per thread in bin_edges
#define EPB (EPT * 256)                // 4096 edges per block
#define BIN_BLOCKS ((N_EDGES + EPB - 1) / EPB)   // 306

// ---------------------------------------------------------------------------
// Workspace layout (bytes):
//   packed  @ 0          : NBUCK*CAP int2 = 16,015,360  (src|dlocal<<20, e)
//   gcursor @ 16,015,360 : NBUCK i32      =      3,128
//   g16     @ 16,019,456 : N*64 bf16      = 12,800,000  (bf16(h @ W^T))
// total ~= 28.8 MB
// ---------------------------------------------------------------------------

__device__ __forceinline__ unsigned bf16_rne(float x) {
    unsigned u = __float_as_uint(x);
    return (u + 0x7FFFu + ((u >> 16) & 1u)) >> 16;
}
__device__ __forceinline__ unsigned pack_bf16x2(float lo, float hi) {
    return bf16_rne(lo) | (bf16_rne(hi) << 16);
}
__device__ __forceinline__ float bf16_to_f(unsigned short v) {
    return __uint_as_float(((unsigned)v) << 16);
}

// g16 = bf16(h @ W^T). LDS-staged fp32 vector GEMM, bf16 pack on store.
__global__ __launch_bounds__(256) void transform_kernel(const float* __restrict__ h,
                                                        const float* __restrict__ W,
                                                        unsigned short* __restrict__ g16) {
    __shared__ float4 hs[64 * 17];
    __shared__ float4 ws4[64 * 17];
    int t = threadIdx.x;
    int n0 = blockIdx.x * 64;
#pragma unroll
    for (int k = 0; k < 4; ++k) {
        int f = t + k * 256;
        int r = f >> 4, c = f & 15;
        float4 hv = make_float4(0.f, 0.f, 0.f, 0.f);
        if (n0 + r < N_NODES) hv = ((const float4*)h)[(n0 + r) * 16 + c];
        hs[r * 17 + c] = hv;
        ws4[r * 17 + c] = ((const float4*)W)[f];
    }
    __syncthreads();

    int r = t >> 2;
    int oq = t & 3;
    float acc[16];
#pragma unroll
    for (int j = 0; j < 16; ++j) acc[j] = 0.f;

    for (int d4 = 0; d4 < 16; ++d4) {
        float4 hv = hs[r * 17 + d4];
#pragma unroll
        for (int j = 0; j < 16; ++j) {
            float4 wv = ws4[(oq * 16 + j) * 17 + d4];
            acc[j] += hv.x * wv.x + hv.y * wv.y + hv.z * wv.z + hv.w * wv.w;
        }
    }

    int n = n0 + r;
    if (n < N_NODES) {
        unsigned u[8];
#pragma unroll
        for (int j = 0; j < 8; ++j) u[j] = pack_bf16x2(acc[2 * j], acc[2 * j + 1]);
        uint4* gr = (uint4*)(g16 + n * D + oq * 16);   // byte offset n*128+oq*32: 32B-aligned
        gr[0] = make_uint4(u[0], u[1], u[2], u[3]);
        gr[1] = make_uint4(u[4], u[5], u[6], u[7]);
    }
}

// Bin edges into fixed-capacity bucket regions with block-level LDS ranking.
// One global reservation per (block,bucket); writes cluster into ~5-edge runs.
__global__ __launch_bounds__(256) void bin_edges_kernel(const int* __restrict__ src,
                                                        const int* __restrict__ dst,
                                                        const float* __restrict__ e,
                                                        int* __restrict__ gcursor,
                                                        int2* __restrict__ packed) {
    __shared__ int lhist[NBUCK];   // counts, then reused as per-block base
    int t = threadIdx.x;
    for (int j = t; j < NBUCK; j += 256) lhist[j] = 0;
    __syncthreads();

    int b[EPT], r[EPT], sv[EPT];
    float ev[EPT];
    int base = blockIdx.x * EPB;
#pragma unroll
    for (int j = 0; j < EPT; ++j) {
        int i = base + j * 256 + t;
        b[j] = -1;
        if (i < N_EDGES) {
            int d = dst[i];
            b[j] = d >> BUCKET_BITS;
            sv[j] = src[i] | ((d & (BUCKET_SZ - 1)) << 20);
            ev[j] = e[i];
            r[j] = atomicAdd(&lhist[b[j]], 1);
        }
    }
    __syncthreads();

    for (int x = t; x < NBUCK; x += 256) {
        int c = lhist[x];
        lhist[x] = (c > 0) ? atomicAdd(&gcursor[x], c) : 0;
    }
    __syncthreads();

#pragma unroll
    for (int j = 0; j < EPT; ++j) {
        if (b[j] >= 0) {
            int pos = lhist[b[j]] + r[j];
            if (pos < CAP) packed[b[j] * CAP + pos] = make_int2(sv[j], __float_as_int(ev[j]));
        }
    }
}

// Per-bucket gather: counting-sort edges by node in LDS, then one wave per
// node: lane d accumulates feature d over bf16 g-rows; + bias; fp32 out.
__global__ __launch_bounds__(256) void gather_bucket_kernel(const unsigned short* __restrict__ g16,
                                                            const int2* __restrict__ packed,
                                                            const int* __restrict__ gcursor,
                                                            const float* __restrict__ bias,
                                                            float* __restrict__ out) {
    __shared__ int2 eds[CAP];
    __shared__ int nhist[BUCKET_SZ];
    __shared__ int nbase[BUCKET_SZ];
    __shared__ int ncur[BUCKET_SZ];
    __shared__ int tmp[BUCKET_SZ];

    int t = threadIdx.x;
    int bk = blockIdx.x;
    int start = bk * CAP;
    int cnt = gcursor[bk];
    if (cnt > CAP) cnt = CAP;

    if (t < BUCKET_SZ) nhist[t] = 0;
    __syncthreads();

    // pass 1: per-node histogram
    for (int i = t; i < cnt; i += 256) {
        int2 p = packed[start + i];
        atomicAdd(&nhist[(p.x >> 20) & (BUCKET_SZ - 1)], 1);
    }
    __syncthreads();

    // exclusive scan of 128 bins
    if (t < BUCKET_SZ) tmp[t] = nhist[t];
    __syncthreads();
#pragma unroll
    for (int off = 1; off < BUCKET_SZ; off <<= 1) {
        int x = 0;
        if (t < BUCKET_SZ && t >= off) x = tmp[t - off];
        __syncthreads();
        if (t < BUCKET_SZ) tmp[t] += x;
        __syncthreads();
    }
    if (t < BUCKET_SZ) {
        int s = tmp[t] - nhist[t];
        nbase[t] = s;
        ncur[t] = s;
    }
    __syncthreads();

    // pass 2: scatter into node-sorted LDS order (packed region is L2-hot)
    for (int i = t; i < cnt; i += 256) {
        int2 p = packed[start + i];
        int dl = (p.x >> 20) & (BUCKET_SZ - 1);
        int pos = atomicAdd(&ncur[dl], 1);
        eds[pos] = p;
    }
    __syncthreads();

    // per-node gather: wave w handles nodes [w*32, w*32+32)
    int w = t >> 6;
    int lane = t & 63;
    float bv = bias[lane];
    for (int jj = 0; jj < 32; ++jj) {
        int n = w * 32 + jj;
        int gn = bk * BUCKET_SZ + n;
        int s = nbase[n];
        int c = nhist[n];
        float acc = bv;
        int k = 0;
        for (; k + 4 <= c; k += 4) {
            int2 p0 = eds[s + k];
            int2 p1 = eds[s + k + 1];
            int2 p2 = eds[s + k + 2];
            int2 p3 = eds[s + k + 3];
            float g0 = bf16_to_f(g16[(p0.x & 0xFFFFF) * D + lane]);
            float g1 = bf16_to_f(g16[(p1.x & 0xFFFFF) * D + lane]);
            float g2 = bf16_to_f(g16[(p2.x & 0xFFFFF) * D + lane]);
            float g3 = bf16_to_f(g16[(p3.x & 0xFFFFF) * D + lane]);
            acc += __int_as_float(p0.y) * g0;
            acc += __int_as_float(p1.y) * g1;
            acc += __int_as_float(p2.y) * g2;
            acc += __int_as_float(p3.y) * g3;
        }
        for (; k < c; ++k) {
            int2 p = eds[s + k];
            acc += __int_as_float(p.y) * bf16_to_f(g16[(p.x & 0xFFFFF) * D + lane]);
        }
        if (gn < N_NODES) out[gn * D + lane] = acc;
    }
}

// ---------------------------------------------------------------------------
extern "C" void kernel_launch(void* const* d_in, const int* in_sizes, int n_in,
                              void* d_out, int out_size, void* d_ws, size_t ws_size,
                              hipStream_t stream) {
    const float* h   = (const float*)d_in[0];
    const float* e   = (const float*)d_in[1];
    const int*   src = (const int*)d_in[2];
    const int*   dst = (const int*)d_in[3];
    const float* W   = (const float*)d_in[4];
    const float* b   = (const float*)d_in[5];
    float* out = (float*)d_out;

    char* ws = (char*)d_ws;
    int2*           packed  = (int2*)          (ws);
    int*            gcursor = (int*)           (ws + 16015360);
    unsigned short* g16     = (unsigned short*)(ws + 16019456);

    // 1) g16 = bf16(h @ W^T)
    transform_kernel<<<(N_NODES + 63) / 64, 256, 0, stream>>>(h, W, g16);

    // 2) fixed-capacity bucket binning (no histogram / scan needed)
    hipMemsetAsync(gcursor, 0, NBUCK * sizeof(int), stream);
    bin_edges_kernel<<<BIN_BLOCKS, 256, 0, stream>>>(src, dst, e, gcursor, packed);

    // 3) per-bucket LDS node-sort + gather + bias
    gather_bucket_kernel<<<NBUCK, 256, 0, stream>>>(g16, packed, gcursor, b, out);
}

// Round 8
// 209.892 us; speedup vs baseline: 4.6879x; 1.0709x over previous
//
#include <hip/hip_runtime.h>

#define N_NODES 100000
#define N_EDGES 1250000
#define D 64
#define BUCKET_BITS 6                  // 64 nodes / bucket
#define BUCKET_SZ 64
#define NBUCK 1563                     // ceil(100000/64)
#define CAP 1408                       // fixed bucket capacity (mean 800, sigma ~28; +21 sigma)
#define EPT 8                          // edges per thread in bin_edges
#define EPB (EPT * 256)                // 2048 edges per block
#define BIN_BLOCKS ((N_EDGES + EPB - 1) / EPB)   // 611

// ---------------------------------------------------------------------------
// Workspace layout (bytes):
//   packed  @ 0          : NBUCK*CAP int2 = 17,605,632  (src|dlocal<<20, e)
//   gcursor @ 17,605,632 : NBUCK i32      =      6,252
//   g16     @ 17,612,800 : N*64 bf16      = 12,800,000  (bf16(h @ W^T))
// total ~= 30.4 MB
// ---------------------------------------------------------------------------

__device__ __forceinline__ unsigned bf16_rne(float x) {
    unsigned u = __float_as_uint(x);
    return (u + 0x7FFFu + ((u >> 16) & 1u)) >> 16;
}
__device__ __forceinline__ unsigned pack_bf16x2(float lo, float hi) {
    return bf16_rne(lo) | (bf16_rne(hi) << 16);
}
__device__ __forceinline__ float bf16_to_f(unsigned short v) {
    return __uint_as_float(((unsigned)v) << 16);
}

// g16 = bf16(h @ W^T). LDS-staged fp32 vector GEMM, bf16 pack on store.
__global__ __launch_bounds__(256) void transform_kernel(const float* __restrict__ h,
                                                        const float* __restrict__ W,
                                                        unsigned short* __restrict__ g16) {
    __shared__ float4 hs[64 * 17];
    __shared__ float4 ws4[64 * 17];
    int t = threadIdx.x;
    int n0 = blockIdx.x * 64;
#pragma unroll
    for (int k = 0; k < 4; ++k) {
        int f = t + k * 256;
        int r = f >> 4, c = f & 15;
        float4 hv = make_float4(0.f, 0.f, 0.f, 0.f);
        if (n0 + r < N_NODES) hv = ((const float4*)h)[(n0 + r) * 16 + c];
        hs[r * 17 + c] = hv;
        ws4[r * 17 + c] = ((const float4*)W)[f];
    }
    __syncthreads();

    int r = t >> 2;
    int oq = t & 3;
    float acc[16];
#pragma unroll
    for (int j = 0; j < 16; ++j) acc[j] = 0.f;

    for (int d4 = 0; d4 < 16; ++d4) {
        float4 hv = hs[r * 17 + d4];
#pragma unroll
        for (int j = 0; j < 16; ++j) {
            float4 wv = ws4[(oq * 16 + j) * 17 + d4];
            acc[j] += hv.x * wv.x + hv.y * wv.y + hv.z * wv.z + hv.w * wv.w;
        }
    }

    int n = n0 + r;
    if (n < N_NODES) {
        unsigned u[8];
#pragma unroll
        for (int j = 0; j < 8; ++j) u[j] = pack_bf16x2(acc[2 * j], acc[2 * j + 1]);
        uint4* gr = (uint4*)(g16 + n * D + oq * 16);
        gr[0] = make_uint4(u[0], u[1], u[2], u[3]);
        gr[1] = make_uint4(u[4], u[5], u[6], u[7]);
    }
}

// Bin edges into fixed-capacity bucket regions with block-level LDS ranking.
__global__ __launch_bounds__(256) void bin_edges_kernel(const int* __restrict__ src,
                                                        const int* __restrict__ dst,
                                                        const float* __restrict__ e,
                                                        int* __restrict__ gcursor,
                                                        int2* __restrict__ packed) {
    __shared__ int lhist[NBUCK];   // counts, then reused as per-block base
    int t = threadIdx.x;
    for (int j = t; j < NBUCK; j += 256) lhist[j] = 0;
    __syncthreads();

    int b[EPT], r[EPT], sv[EPT];
    float ev[EPT];
    int base = blockIdx.x * EPB;
#pragma unroll
    for (int j = 0; j < EPT; ++j) {
        int i = base + j * 256 + t;
        b[j] = -1;
        if (i < N_EDGES) {
            int d = dst[i];
            b[j] = d >> BUCKET_BITS;
            sv[j] = src[i] | ((d & (BUCKET_SZ - 1)) << 20);
            ev[j] = e[i];
            r[j] = atomicAdd(&lhist[b[j]], 1);
        }
    }
    __syncthreads();

    for (int x = t; x < NBUCK; x += 256) {
        int c = lhist[x];
        lhist[x] = (c > 0) ? atomicAdd(&gcursor[x], c) : 0;
    }
    __syncthreads();

#pragma unroll
    for (int j = 0; j < EPT; ++j) {
        if (b[j] >= 0) {
            int pos = lhist[b[j]] + r[j];
            if (pos < CAP) packed[b[j] * CAP + pos] = make_int2(sv[j], __float_as_int(ev[j]));
        }
    }
}

// Per-bucket gather: counting-sort edges by node in LDS, then one wave per
// 16-node group: lane d accumulates feature d over bf16 g-rows; +bias; out.
__global__ __launch_bounds__(256) void gather_bucket_kernel(const unsigned short* __restrict__ g16,
                                                            const int2* __restrict__ packed,
                                                            const int* __restrict__ gcursor,
                                                            const float* __restrict__ bias,
                                                            float* __restrict__ out) {
    __shared__ int2 eds[CAP];
    __shared__ int nhist[BUCKET_SZ];
    __shared__ int nbase[BUCKET_SZ];
    __shared__ int ncur[BUCKET_SZ];
    __shared__ int tmp[BUCKET_SZ];

    int t = threadIdx.x;
    int bk = blockIdx.x;
    int start = bk * CAP;
    int cnt = gcursor[bk];
    if (cnt > CAP) cnt = CAP;

    if (t < BUCKET_SZ) nhist[t] = 0;
    __syncthreads();

    // pass 1: per-node histogram
    for (int i = t; i < cnt; i += 256) {
        int2 p = packed[start + i];
        atomicAdd(&nhist[(p.x >> 20) & (BUCKET_SZ - 1)], 1);
    }
    __syncthreads();

    // exclusive scan of 64 bins
    if (t < BUCKET_SZ) tmp[t] = nhist[t];
    __syncthreads();
#pragma unroll
    for (int off = 1; off < BUCKET_SZ; off <<= 1) {
        int x = 0;
        if (t < BUCKET_SZ && t >= off) x = tmp[t - off];
        __syncthreads();
        if (t < BUCKET_SZ) tmp[t] += x;
        __syncthreads();
    }
    if (t < BUCKET_SZ) {
        int s = tmp[t] - nhist[t];
        nbase[t] = s;
        ncur[t] = s;
    }
    __syncthreads();

    // pass 2: scatter into node-sorted LDS order (packed region is L2-hot)
    for (int i = t; i < cnt; i += 256) {
        int2 p = packed[start + i];
        int dl = (p.x >> 20) & (BUCKET_SZ - 1);
        int pos = atomicAdd(&ncur[dl], 1);
        eds[pos] = p;
    }
    __syncthreads();

    // per-node gather: wave w handles nodes [w*16, w*16+16)
    int w = t >> 6;
    int lane = t & 63;
    float bv = bias[lane];
    for (int jj = 0; jj < 16; ++jj) {
        int n = w * 16 + jj;
        int gn = bk * BUCKET_SZ + n;
        int s = nbase[n];
        int c = nhist[n];
        float acc = bv;
        int k = 0;
        for (; k + 4 <= c; k += 4) {
            int2 p0 = eds[s + k];
            int2 p1 = eds[s + k + 1];
            int2 p2 = eds[s + k + 2];
            int2 p3 = eds[s + k + 3];
            float g0 = bf16_to_f(g16[(p0.x & 0xFFFFF) * D + lane]);
            float g1 = bf16_to_f(g16[(p1.x & 0xFFFFF) * D + lane]);
            float g2 = bf16_to_f(g16[(p2.x & 0xFFFFF) * D + lane]);
            float g3 = bf16_to_f(g16[(p3.x & 0xFFFFF) * D + lane]);
            acc += __int_as_float(p0.y) * g0;
            acc += __int_as_float(p1.y) * g1;
            acc += __int_as_float(p2.y) * g2;
            acc += __int_as_float(p3.y) * g3;
        }
        for (; k < c; ++k) {
            int2 p = eds[s + k];
            acc += __int_as_float(p.y) * bf16_to_f(g16[(p.x & 0xFFFFF) * D + lane]);
        }
        if (gn < N_NODES) out[gn * D + lane] = acc;
    }
}

// ---------------------------------------------------------------------------
extern "C" void kernel_launch(void* const* d_in, const int* in_sizes, int n_in,
                              void* d_out, int out_size, void* d_ws, size_t ws_size,
                              hipStream_t stream) {
    const float* h   = (const float*)d_in[0];
    const float* e   = (const float*)d_in[1];
    const int*   src = (const int*)d_in[2];
    const int*   dst = (const int*)d_in[3];
    const float* W   = (const float*)d_in[4];
    const float* b   = (const float*)d_in[5];
    float* out = (float*)d_out;

    char* ws = (char*)d_ws;
    int2*           packed  = (int2*)          (ws);
    int*            gcursor = (int*)           (ws + 17605632);
    unsigned short* g16     = (unsigned short*)(ws + 17612800);

    // 1) g16 = bf16(h @ W^T)
    transform_kernel<<<(N_NODES + 63) / 64, 256, 0, stream>>>(h, W, g16);

    // 2) fixed-capacity bucket binning
    hipMemsetAsync(gcursor, 0, NBUCK * sizeof(int), stream);
    bin_edges_kernel<<<BIN_BLOCKS, 256, 0, stream>>>(src, dst, e, gcursor, packed);

    // 3) per-bucket LDS node-sort + gather + bias
    gather_bucket_kernel<<<NBUCK, 256, 0, stream>>>(g16, packed, gcursor, b, out);
}